// Round 14
// baseline (2379.855 us; speedup 1.0000x reference)
//
#include <hip/hip_runtime.h>

#define BB 32
#define TT 1000
#define HH 512
#define G4 2048
#define BTH ((size_t)BB * TT * HH)  // elements per output tensor

typedef short short8 __attribute__((ext_vector_type(8)));
typedef float f32x4 __attribute__((ext_vector_type(4)));
typedef unsigned long long ull;

__device__ __forceinline__ unsigned short f2bf(float f) {
    union { float f; unsigned u; } v; v.f = f;
    unsigned r = v.u + 0x7FFF + ((v.u >> 16) & 1);  // RNE; inputs finite
    return (unsigned short)(r >> 16);
}

// ring: u32 words [2 slots][8 groups][32 producers x 64 words]
// word = (bf16(h) << 16) | t  -- self-tagged, fence-free (R2/R9-proven protocol)
#define RING_WORDS (2 * 8 * 32 * 64)   // 32768 u32 = 128KB (proven within ws_size)

__global__ void lstm_init_ring(unsigned* ring) {
    int i = blockIdx.x * 256 + threadIdx.x;
    __hip_atomic_store(ring + i, 0xFFFFFFFFu, __ATOMIC_RELAXED,
                       __HIP_MEMORY_SCOPE_AGENT);
}

// LDS-ordering-only barrier (R9-validated): VMEM stays in flight.
#define LDS_BAR() do {                                      \
    asm volatile("s_waitcnt lgkmcnt(0)" ::: "memory");      \
    __builtin_amdgcn_s_barrier();                           \
    asm volatile("" ::: "memory");                          \
    __builtin_amdgcn_sched_barrier(0);                      \
} while (0)

__global__ void __launch_bounds__(256, 1)
lstm_main(const float* __restrict__ wx, const float* __restrict__ u,
          const float* __restrict__ ub, const float* __restrict__ ht0,
          const float* __restrict__ ct0, float* __restrict__ out,
          unsigned* __restrict__ ring)
{
    // K-split partial sums only; h never touches LDS. Double-buffered.
    __shared__ __align__(16) float part[2][4][4][16][4];   // [buf][wave][gate][jc][batch] = 8KB

    const int tid  = threadIdx.x;
    const int bid  = blockIdx.x;
    const int cg   = bid & 31;   // owns h/gate cols [cg*16, cg*16+16)
    const int qb   = bid >> 5;   // owns batches [qb*4, qb*4+4)
    const int lane = tid & 63;
    const int wv   = tid >> 6;   // wave: K-slice [128*wv, 128*wv+128)
    const int arow = lane & 15;  // A row (batch; rows 4-15 are zero pads)
    const int ahi  = lane >> 4;

    // ---- poll addressing: A-frag k = 128wv + 32kk + 8ahi + e maps to
    //      producer p(kk) = 8wv + 2kk + (ahi>>1), word = arow*16 + (ahi&1)*8+e ----
    const int woff = arow * 16 + (ahi & 1) * 8;
    const int p0 = 8 * wv + 0 + (ahi >> 1), p1 = 8 * wv + 2 + (ahi >> 1);
    const int p2 = 8 * wv + 4 + (ahi >> 1), p3 = 8 * wv + 6 + (ahi >> 1);

    // ---- initial A-frags from ht0 (bf16); zeros for pad rows ----
    short8 a0 = {0,0,0,0,0,0,0,0}, a1 = a0, a2 = a0, a3 = a0;
    if (arow < 4) {
        const float* hp = ht0 + (size_t)(qb * 4 + arow) * HH + 128 * wv + 8 * ahi;
#define INITA(dst, kk) do {                                                   \
        float4 v0 = *(const float4*)(hp + (kk) * 32);                         \
        float4 v1 = *(const float4*)(hp + (kk) * 32 + 4);                     \
        union { short8 v8; unsigned short s[8]; } p;                          \
        p.s[0]=f2bf(v0.x); p.s[1]=f2bf(v0.y); p.s[2]=f2bf(v0.z); p.s[3]=f2bf(v0.w); \
        p.s[4]=f2bf(v1.x); p.s[5]=f2bf(v1.y); p.s[6]=f2bf(v1.z); p.s[7]=f2bf(v1.w); \
        dst = p.v8; } while (0)
        INITA(a0, 0); INITA(a1, 1); INITA(a2, 2); INITA(a3, 3);
#undef INITA
    }

    // ---- preload u fragments: breg[g*4+kk], B col = arow -> u row g*512+cg*16+arow,
    //      k = 128wv + 32kk + 8ahi ----
    short8 breg[16];
    {
#pragma unroll
        for (int g = 0; g < 4; ++g) {
            const float* bp = u + (size_t)(g * HH + cg * 16 + arow) * HH +
                              128 * wv + 8 * ahi;
#pragma unroll
            for (int kk = 0; kk < 4; ++kk) {
                float4 v0 = *(const float4*)(bp + kk * 32);
                float4 v1 = *(const float4*)(bp + kk * 32 + 4);
                union { short8 v8; unsigned short s[8]; } p;
                p.s[0]=f2bf(v0.x); p.s[1]=f2bf(v0.y); p.s[2]=f2bf(v0.z); p.s[3]=f2bf(v0.w);
                p.s[4]=f2bf(v1.x); p.s[5]=f2bf(v1.y); p.s[6]=f2bf(v1.z); p.s[7]=f2bf(v1.w);
                breg[g * 4 + kk] = p.v8;
            }
        }
    }

    // ---- epilogue mapping (R9-exact): batch = wv, gate-col = lane ----
    const int gate = lane >> 4;
    const int jc   = lane & 15;
    const float bias_r = ub[gate * HH + cg * 16 + jc];

    float c_reg = 0.f;
    if (lane < 16)
        c_reg = ct0[(size_t)(qb * 4 + wv) * HH + cg * 16 + lane];

    const size_t wx0 = (size_t)(qb * 4 + wv) * TT * G4 + gate * HH + cg * 16 + jc;
    float wx_cur = wx[wx0];
    float wx_nxt = wx[wx0 + G4];

    const size_t ob_gate = (size_t)(2 + gate) * BTH +
                           (size_t)(qb * 4 + wv) * TT * HH + cg * 16 + jc;
    const size_t ob_h = (size_t)(qb * 4 + wv) * TT * HH + cg * 16 + lane;

    __syncthreads();   // setup complete

    for (int t = 0; t < TT; ++t) {
        const int cur = t & 1;

        // ---- phase 1: per-wave poll of its OWN 8 producers -> A-frags direct ----
        if (t > 0 && arow < 4) {
            const size_t slotbase = ((size_t)((t - 1) & 1) * 8 + qb) * 2048;
            const ull* s0 = (const ull*)(ring + slotbase + p0 * 64 + woff);
            const ull* s1 = (const ull*)(ring + slotbase + p1 * 64 + woff);
            const ull* s2 = (const ull*)(ring + slotbase + p2 * 64 + woff);
            const ull* s3 = (const ull*)(ring + slotbase + p3 * 64 + woff);
            const unsigned tg = (unsigned)(t - 1);
            const ull want = (ull)tg | ((ull)tg << 32);
            const ull msk = 0x0000FFFF0000FFFFull;
            ull q00,q01,q02,q03, q10,q11,q12,q13, q20,q21,q22,q23, q30,q31,q32,q33;
            for (;;) {
#define LD4(qa,qb_,qc,qd,sp) do { \
                qa = __hip_atomic_load(sp+0, __ATOMIC_RELAXED, __HIP_MEMORY_SCOPE_AGENT); \
                qb_= __hip_atomic_load(sp+1, __ATOMIC_RELAXED, __HIP_MEMORY_SCOPE_AGENT); \
                qc = __hip_atomic_load(sp+2, __ATOMIC_RELAXED, __HIP_MEMORY_SCOPE_AGENT); \
                qd = __hip_atomic_load(sp+3, __ATOMIC_RELAXED, __HIP_MEMORY_SCOPE_AGENT); } while (0)
                LD4(q00,q01,q02,q03, s0); LD4(q10,q11,q12,q13, s1);
                LD4(q20,q21,q22,q23, s2); LD4(q30,q31,q32,q33, s3);
#undef LD4
                bool ok = ((q00&msk)==want)&((q01&msk)==want)&((q02&msk)==want)&((q03&msk)==want)
                        & ((q10&msk)==want)&((q11&msk)==want)&((q12&msk)==want)&((q13&msk)==want)
                        & ((q20&msk)==want)&((q21&msk)==want)&((q22&msk)==want)&((q23&msk)==want)
                        & ((q30&msk)==want)&((q31&msk)==want)&((q32&msk)==want)&((q33&msk)==want);
                if (ok) break;
            }
#define PACK(dst, qa,qb_,qc,qd) do {                                          \
            union { short8 v8; unsigned u[4]; } pv;                           \
            pv.u[0] = ((unsigned)(qa >> 16) & 0xFFFFu) | ((unsigned)(qa >> 48) << 16); \
            pv.u[1] = ((unsigned)(qb_>> 16) & 0xFFFFu) | ((unsigned)(qb_>> 48) << 16); \
            pv.u[2] = ((unsigned)(qc >> 16) & 0xFFFFu) | ((unsigned)(qc >> 48) << 16); \
            pv.u[3] = ((unsigned)(qd >> 16) & 0xFFFFu) | ((unsigned)(qd >> 48) << 16); \
            dst = pv.v8; } while (0)
            PACK(a0, q00,q01,q02,q03); PACK(a1, q10,q11,q12,q13);
            PACK(a2, q20,q21,q22,q23); PACK(a3, q30,q31,q32,q33);
#undef PACK
        }

        const float wx_use = wx_cur;
        wx_cur = wx_nxt;
        if (t + 2 < TT) wx_nxt = wx[wx0 + (size_t)(t + 2) * G4];   // R9 position

        // ---- phase 2: 16 MFMAs, 4 independent chains (one per gate) ----
        f32x4 g0 = {0.f,0.f,0.f,0.f}, g1 = g0, g2 = g0, g3 = g0;
        g0 = __builtin_amdgcn_mfma_f32_16x16x32_bf16(a0, breg[0],  g0, 0, 0, 0);
        g1 = __builtin_amdgcn_mfma_f32_16x16x32_bf16(a0, breg[4],  g1, 0, 0, 0);
        g2 = __builtin_amdgcn_mfma_f32_16x16x32_bf16(a0, breg[8],  g2, 0, 0, 0);
        g3 = __builtin_amdgcn_mfma_f32_16x16x32_bf16(a0, breg[12], g3, 0, 0, 0);
        g0 = __builtin_amdgcn_mfma_f32_16x16x32_bf16(a1, breg[1],  g0, 0, 0, 0);
        g1 = __builtin_amdgcn_mfma_f32_16x16x32_bf16(a1, breg[5],  g1, 0, 0, 0);
        g2 = __builtin_amdgcn_mfma_f32_16x16x32_bf16(a1, breg[9],  g2, 0, 0, 0);
        g3 = __builtin_amdgcn_mfma_f32_16x16x32_bf16(a1, breg[13], g3, 0, 0, 0);
        g0 = __builtin_amdgcn_mfma_f32_16x16x32_bf16(a2, breg[2],  g0, 0, 0, 0);
        g1 = __builtin_amdgcn_mfma_f32_16x16x32_bf16(a2, breg[6],  g1, 0, 0, 0);
        g2 = __builtin_amdgcn_mfma_f32_16x16x32_bf16(a2, breg[10], g2, 0, 0, 0);
        g3 = __builtin_amdgcn_mfma_f32_16x16x32_bf16(a2, breg[14], g3, 0, 0, 0);
        g0 = __builtin_amdgcn_mfma_f32_16x16x32_bf16(a3, breg[3],  g0, 0, 0, 0);
        g1 = __builtin_amdgcn_mfma_f32_16x16x32_bf16(a3, breg[7],  g1, 0, 0, 0);
        g2 = __builtin_amdgcn_mfma_f32_16x16x32_bf16(a3, breg[11], g2, 0, 0, 0);
        g3 = __builtin_amdgcn_mfma_f32_16x16x32_bf16(a3, breg[15], g3, 0, 0, 0);

        // partial store (lanes<16 hold batches 0-3); buf reuse at t+2 is ordered
        // after all reads at t via the inter-block publish/poll dependence chain.
        if (lane < 16) {
            *(f32x4*)&part[cur][wv][0][lane][0] = g0;
            *(f32x4*)&part[cur][wv][1][lane][0] = g1;
            *(f32x4*)&part[cur][wv][2][lane][0] = g2;
            *(f32x4*)&part[cur][wv][3][lane][0] = g3;
        }
        LDS_BAR();   // the ONLY barrier per step

        // ---- phase 3: reduce partials + activations + publish (R9-exact) ----
        float gv = part[cur][0][gate][jc][wv] + part[cur][1][gate][jc][wv]
                 + part[cur][2][gate][jc][wv] + part[cur][3][gate][jc][wv]
                 + wx_use + bias_r;
        float xs = (gate == 2) ? 2.f * gv : gv;
        float s  = 1.f / (1.f + __expf(-xs));
        float act = (gate == 2) ? 2.f * s - 1.f : s;  // tanh = 2*sigmoid(2x)-1

        float af = __shfl(act, (lane & 15) + 16, 64);
        float ag = __shfl(act, (lane & 15) + 32, 64);
        float ao = __shfl(act, (lane & 15) + 48, 64);
        if (lane < 16) {
            c_reg = af * c_reg + act * ag;
            float e2 = __expf(-2.f * c_reg);
            float th = 2.f / (1.f + e2) - 1.f;
            float hn = ao * th;
            unsigned short hb = f2bf(hn);
            // publish FIRST (critical inter-block path)
            unsigned pk = ((unsigned)hb << 16) | (unsigned)t;
            __hip_atomic_store(ring + ((size_t)(t & 1) * 8 + qb) * 2048 +
                                   cg * 64 + wv * 16 + lane,
                               pk, __ATOMIC_RELAXED, __HIP_MEMORY_SCOPE_AGENT);
            out[ob_h + (size_t)t * HH] = hn;
            out[BTH + ob_h + (size_t)t * HH] = c_reg;
        }
        out[ob_gate + (size_t)t * HH] = act;
    }
}

extern "C" void kernel_launch(void* const* d_in, const int* in_sizes, int n_in,
                              void* d_out, int out_size, void* d_ws, size_t ws_size,
                              hipStream_t stream) {
    const float* wx = (const float*)d_in[0];
    const float* u  = (const float*)d_in[1];
    const float* ub = (const float*)d_in[2];
    const float* ht = (const float*)d_in[3];
    const float* ct = (const float*)d_in[4];
    float* out = (float*)d_out;
    unsigned* ring = (unsigned*)d_ws;   // 128KB, proven within ws_size

    lstm_init_ring<<<RING_WORDS / 256, 256, 0, stream>>>(ring);

    void* args[] = {(void*)&wx, (void*)&u, (void*)&ub, (void*)&ht,
                    (void*)&ct, (void*)&out, (void*)&ring};
    hipLaunchCooperativeKernel((void*)lstm_main, dim3(256), dim3(256), args, 0, stream);
}

// Round 15
// 1700.929 us; speedup vs baseline: 1.3991x; 1.3991x over previous
//
#include <hip/hip_runtime.h>

#define BB 32
#define TT 1000
#define HH 512
#define G4 2048
#define BTH ((size_t)BB * TT * HH)  // elements per output tensor

typedef short short8 __attribute__((ext_vector_type(8)));
typedef float f32x4 __attribute__((ext_vector_type(4)));

__device__ __forceinline__ unsigned short f2bf(float f) {
    union { float f; unsigned u; } v; v.f = f;
    unsigned r = v.u + 0x7FFF + ((v.u >> 16) & 1);  // RNE; inputs finite
    return (unsigned short)(r >> 16);
}

// ring: u32 words [2 slots][8 groups][32 producers x 64 words]
// word = (bf16(h) << 16) | t  -- self-tagged, fence-free (R2/R9-proven protocol)
#define RING_WORDS (2 * 8 * 32 * 64)   // 32768 u32 = 128KB (proven within ws_size)

__global__ void lstm_init_ring(unsigned* ring) {
    int i = blockIdx.x * 256 + threadIdx.x;
    __hip_atomic_store(ring + i, 0xFFFFFFFFu, __ATOMIC_RELAXED,
                       __HIP_MEMORY_SCOPE_AGENT);
}

// LDS-ordering-only barrier (R9-validated): VMEM stays in flight.
#define LDS_BAR() do {                                      \
    asm volatile("s_waitcnt lgkmcnt(0)" ::: "memory");      \
    __builtin_amdgcn_s_barrier();                           \
    asm volatile("" ::: "memory");                          \
    __builtin_amdgcn_sched_barrier(0);                      \
} while (0)

__global__ void __launch_bounds__(256, 1)
lstm_main(const float* __restrict__ wx, const float* __restrict__ u,
          const float* __restrict__ ub, const float* __restrict__ ht0,
          const float* __restrict__ ct0, float* __restrict__ out,
          unsigned* __restrict__ ring)
{
    __shared__ __align__(16) unsigned short lds_h[16 * 512];  // 16KB, XOR-swizzled
    __shared__ float lds_gates[4 * 64];

    const int tid  = threadIdx.x;
    const int bid  = blockIdx.x;
    const int cg   = bid & 31;   // owns h/gate cols [cg*16, cg*16+16)
    const int qb   = bid >> 5;   // owns batches [qb*4, qb*4+4)
    const int lane = tid & 63;
    const int wv   = tid >> 6;

    // ---- zero pad rows 4..15 of lds_h ----
    for (int j = 0; j < 3; ++j) {
        int idx8 = tid + j * 256;
        int r = 4 + (idx8 >> 6);
        int k = (idx8 & 63) * 8;
        short8 z = {0, 0, 0, 0, 0, 0, 0, 0};
        *(short8*)&lds_h[(r * 512 + k) ^ ((r & 7) << 3)] = z;
    }
    // ---- stage initial h (f32 -> bf16) ----
    {
        int r = wv, k = lane * 8;
        const float* src0 = ht0 + (size_t)(qb * 4 + r) * HH + k;
        float4 v0 = *(const float4*)src0;
        float4 v1 = *(const float4*)(src0 + 4);
        union { short8 v8; unsigned short s[8]; } p;
        p.s[0] = f2bf(v0.x); p.s[1] = f2bf(v0.y); p.s[2] = f2bf(v0.z); p.s[3] = f2bf(v0.w);
        p.s[4] = f2bf(v1.x); p.s[5] = f2bf(v1.y); p.s[6] = f2bf(v1.z); p.s[7] = f2bf(v1.w);
        *(short8*)&lds_h[(r * 512 + k) ^ ((r & 7) << 3)] = p.v8;
    }

    // ---- preload u fragments into registers (loop-invariant) ----
    const int arow = lane & 15, ahi = lane >> 4;
    short8 breg[16];
    {
        const float* bp = u + (size_t)(wv * HH + cg * 16 + arow) * HH + ahi * 8;
#pragma unroll
        for (int kk = 0; kk < 16; ++kk) {
            float4 v0 = *(const float4*)(bp + kk * 32);
            float4 v1 = *(const float4*)(bp + kk * 32 + 4);
            union { short8 v8; unsigned short s[8]; } p;
            p.s[0] = f2bf(v0.x); p.s[1] = f2bf(v0.y); p.s[2] = f2bf(v0.z); p.s[3] = f2bf(v0.w);
            p.s[4] = f2bf(v1.x); p.s[5] = f2bf(v1.y); p.s[6] = f2bf(v1.z); p.s[7] = f2bf(v1.w);
            breg[kk] = p.v8;
        }
    }

    const int gate = lane >> 4;
    const int jc   = lane & 15;
    const float bias_r = ub[gate * HH + cg * 16 + jc];

    float c_reg = 0.f;
    if (lane < 16)
        c_reg = ct0[(size_t)(qb * 4 + wv) * HH + cg * 16 + lane];

    const size_t wx0 = (size_t)(qb * 4 + wv) * TT * G4 + gate * HH + cg * 16 + jc;
    float wx_cur = wx[wx0];
    float wx_nxt = wx[wx0 + G4];

    const size_t ob_gate = (size_t)(2 + gate) * BTH +
                           (size_t)(qb * 4 + wv) * TT * HH + cg * 16 + jc;
    const size_t ob_h = (size_t)(qb * 4 + wv) * TT * HH + cg * 16 + lane;

    const int a_off = arow * 512 + ahi * 8;
    const int a_msk = (arow & 7) << 3;

    const int myp = tid >> 3;            // producer 0..31
    const int mw  = (tid & 7) * 8;       // word offset 0..56
    const int mb  = mw >> 4;
    const int mj  = mw & 15;

    __syncthreads();   // setup complete (one full drain, harmless)

    for (int t = 0; t < TT; ++t) {
        // ---- phase 1: acquire h_{t-1} (R2/R9-proven AGENT poll) ----
        if (t > 0 && myp != cg) {
            const unsigned long long* src = (const unsigned long long*)
                (ring + ((size_t)((t - 1) & 1) * 8 + qb) * 2048 + myp * 64 + mw);
            const unsigned tg = (unsigned)(t - 1);
            const unsigned long long want =
                (unsigned long long)tg | ((unsigned long long)tg << 32);
            const unsigned long long msk = 0x0000FFFF0000FFFFull;
            unsigned long long q0, q1, q2, q3;
            for (;;) {
                q0 = __hip_atomic_load(src + 0, __ATOMIC_RELAXED, __HIP_MEMORY_SCOPE_AGENT);
                q1 = __hip_atomic_load(src + 1, __ATOMIC_RELAXED, __HIP_MEMORY_SCOPE_AGENT);
                q2 = __hip_atomic_load(src + 2, __ATOMIC_RELAXED, __HIP_MEMORY_SCOPE_AGENT);
                q3 = __hip_atomic_load(src + 3, __ATOMIC_RELAXED, __HIP_MEMORY_SCOPE_AGENT);
                if (((q0 & msk) == want) & ((q1 & msk) == want) &
                    ((q2 & msk) == want) & ((q3 & msk) == want)) break;
            }
            union { short8 v8; unsigned u[4]; } pv;
            pv.u[0] = ((unsigned)(q0 >> 16) & 0xFFFFu) | ((unsigned)(q0 >> 48) << 16);
            pv.u[1] = ((unsigned)(q1 >> 16) & 0xFFFFu) | ((unsigned)(q1 >> 48) << 16);
            pv.u[2] = ((unsigned)(q2 >> 16) & 0xFFFFu) | ((unsigned)(q2 >> 48) << 16);
            pv.u[3] = ((unsigned)(q3 >> 16) & 0xFFFFu) | ((unsigned)(q3 >> 48) << 16);
            *(short8*)&lds_h[(mb * 512 + myp * 16 + mj) ^ ((mb & 7) << 3)] = pv.v8;
        }
        LDS_BAR();   // S1: LDS ordering only (VMEM stays in flight)

        const float wx_use = wx_cur;
        wx_cur = wx_nxt;
        if (t + 2 < TT) wx_nxt = wx[wx0 + (size_t)(t + 2) * G4];   // proven position

        // ---- phase 2: MFMA (R9-exact) ----
        f32x4 acc0 = {0.f, 0.f, 0.f, 0.f}, acc1 = {0.f, 0.f, 0.f, 0.f};
#pragma unroll
        for (int kk = 0; kk < 8; ++kk) {
            short8 va0 = *(const short8*)&lds_h[(a_off + kk * 32) ^ a_msk];
            short8 va1 = *(const short8*)&lds_h[(a_off + (kk + 8) * 32) ^ a_msk];
            acc0 = __builtin_amdgcn_mfma_f32_16x16x32_bf16(va0, breg[kk], acc0, 0, 0, 0);
            acc1 = __builtin_amdgcn_mfma_f32_16x16x32_bf16(va1, breg[kk + 8], acc1, 0, 0, 0);
        }
        f32x4 g = acc0 + acc1;
        if (lane < 16) {
#pragma unroll
            for (int rr = 0; rr < 4; ++rr)
                lds_gates[rr * 64 + wv * 16 + lane] = g[rr];
        }
        LDS_BAR();   // S2: LDS ordering only

        // ---- phase 3: activations, c/h update, publish (R9-exact) ----
        float gv = lds_gates[wv * 64 + lane] + wx_use + bias_r;
        float xs = (gate == 2) ? 2.f * gv : gv;
        float s  = 1.f / (1.f + __expf(-xs));
        float act = (gate == 2) ? 2.f * s - 1.f : s;  // tanh = 2*sigmoid(2x)-1

        float af = __shfl(act, (lane & 15) + 16, 64);
        float ag = __shfl(act, (lane & 15) + 32, 64);
        float ao = __shfl(act, (lane & 15) + 48, 64);
        if (lane < 16) {
            c_reg = af * c_reg + act * ag;
            float e2 = __expf(-2.f * c_reg);
            float th = 2.f / (1.f + e2) - 1.f;
            float hn = ao * th;
            unsigned short hb = f2bf(hn);
            // publish FIRST (critical inter-block path)
            unsigned pk = ((unsigned)hb << 16) | (unsigned)t;
            __hip_atomic_store(ring + ((size_t)(t & 1) * 8 + qb) * 2048 +
                                   cg * 64 + wv * 16 + lane,
                               pk, __ATOMIC_RELAXED, __HIP_MEMORY_SCOPE_AGENT);
            lds_h[(wv * 512 + cg * 16 + lane) ^ ((wv & 7) << 3)] = hb;
            out[ob_h + (size_t)t * HH] = hn;
            out[BTH + ob_h + (size_t)t * HH] = c_reg;
        }
        out[ob_gate + (size_t)t * HH] = act;
    }
}

extern "C" void kernel_launch(void* const* d_in, const int* in_sizes, int n_in,
                              void* d_out, int out_size, void* d_ws, size_t ws_size,
                              hipStream_t stream) {
    const float* wx = (const float*)d_in[0];
    const float* u  = (const float*)d_in[1];
    const float* ub = (const float*)d_in[2];
    const float* ht = (const float*)d_in[3];
    const float* ct = (const float*)d_in[4];
    float* out = (float*)d_out;
    unsigned* ring = (unsigned*)d_ws;   // 128KB, proven within ws_size

    lstm_init_ring<<<RING_WORDS / 256, 256, 0, stream>>>(ring);

    void* args[] = {(void*)&wx, (void*)&u, (void*)&ub, (void*)&ht,
                    (void*)&ct, (void*)&out, (void*)&ring};
    hipLaunchCooperativeKernel((void*)lstm_main, dim3(256), dim3(256), args, 0, stream);
}